// Round 3
// baseline (604.051 us; speedup 1.0000x reference)
//
#include <hip/hip_runtime.h>
#include <math.h>

// Problem constants (fixed by the reference)
constexpr int kT = 500000;     // history length
constexpr int kQ = 256;        // feature size
constexpr int kH = 256;        // hidden size
constexpr int kK = 32;         // attn_k
constexpr int kNB1 = 256;      // phase-1 top-k blocks
constexpr int kCHUNK = (kT + kNB1 - 1) / kNB1;  // 1954
constexpr int kNC = kNB1 * kK; // 8192 merge candidates
constexpr int kGruRows = 3 * kH;              // 768
constexpr int kGruBlocks = kGruRows / 4;      // 192 (4 waves/block, 1 row/wave)
constexpr int kRowsQs = kT + 1;               // qs_new rows
constexpr int kRowsAll = 2 * kT + 2;          // qs_new + hs_new rows

typedef float f4 __attribute__((ext_vector_type(4)));

// Scratch floats: alpha kT | candV kNC | candI kNC | gi 768 | gh 768 | hnew 256
constexpr size_t kScratchFloats = (size_t)kT + 2 * kNC + 2 * kGruRows + kH;

// ---------------------------------------------------------------------------
// Flat shifted copy with ALIGNED loads and (almost all) ALIGNED stores.
// Output is out[1 + i] = flat_src[i] where flat_src = qs | qh | hs | hnew.
// One wave per 256-float row: aligned f4 loads of the row, then data is
// shifted one float across lanes via shfl_up so stores hit 16B alignment.
// Computes alpha[r] = qs[r] . qh for rows r < kT.
__global__ __launch_bounds__(256) void k_bigcopy(
    const float* __restrict__ qs, const float* __restrict__ hs,
    const float* __restrict__ qh, const float* __restrict__ hnew,
    float* __restrict__ out, float* __restrict__ alpha,
    int rowBegin, int rowEnd) {
  const int lane = threadIdx.x & 63;
  const int wid  = (int)((blockIdx.x * blockDim.x + threadIdx.x) >> 6);
  const int nw   = (int)((gridDim.x * blockDim.x) >> 6);
  const f4 q4 = ((const f4*)qh)[lane];
  for (int r = rowBegin + wid; r < rowEnd; r += nw) {
    const f4* src;
    if (r < kT)               src = (const f4*)(qs + (size_t)r * kQ);
    else if (r == kT)         src = (const f4*)qh;
    else if (r < 2 * kT + 1)  src = (const f4*)(hs + (size_t)(r - kT - 1) * kH);
    else                      src = (const f4*)hnew;
    f4 v = src[lane];
    float pw = __shfl_up(v.w, 1);  // lane l gets lane l-1's element 4l-1
    float* obase = out + 1 + (size_t)r * kQ;     // row start (float idx ≡1 mod 4)
    if (lane > 0) {
      f4 sv; sv.x = pw; sv.y = v.x; sv.z = v.y; sv.w = v.z;
      *(f4*)(obase - 1 + 4 * lane) = sv;         // 16B-aligned dwordx4
    } else {
      obase[0] = v.x; obase[1] = v.y; obase[2] = v.z;
    }
    if (lane == 63) obase[255] = v.w;
    if (r < kT) {
      float d = v.x * q4.x + v.y * q4.y + v.z * q4.z + v.w * q4.w;
#pragma unroll
      for (int off = 32; off; off >>= 1) d += __shfl_xor(d, off);
      if (lane == 0) alpha[r] = d;
    }
  }
}

// ---------------------------------------------------------------------------
// GRU matvecs: one row per wave, 4 waves/block.
__global__ __launch_bounds__(256) void k_gru1(
    const float* __restrict__ Wih, const float* __restrict__ Whh,
    const float* __restrict__ bih, const float* __restrict__ bhh,
    const float* __restrict__ qh, const float* __restrict__ hs,
    const float* __restrict__ score, float* __restrict__ gi,
    float* __restrict__ gh) {
  const int lane = threadIdx.x & 63;
  const int r = blockIdx.x * 4 + (threadIdx.x >> 6);
  const int off = (score[0] >= 0.5f) ? 0 : kQ;  // x = [qh*ge, qh*(1-ge)]
  const float* hprev = hs + (size_t)(kT - 1) * kH;
  f4 q4 = ((const f4*)qh)[lane];
  f4 h4 = ((const f4*)hprev)[lane];
  f4 wi = ((const f4*)(Wih + (size_t)r * (2 * kQ) + off))[lane];
  f4 wh = ((const f4*)(Whh + (size_t)r * kH))[lane];
  float di = wi.x * q4.x + wi.y * q4.y + wi.z * q4.z + wi.w * q4.w;
  float dh = wh.x * h4.x + wh.y * h4.y + wh.z * h4.z + wh.w * h4.w;
#pragma unroll
  for (int o = 32; o; o >>= 1) {
    di += __shfl_xor(di, o);
    dh += __shfl_xor(dh, o);
  }
  if (lane == 0) {
    gi[r] = di + bih[r];
    gh[r] = dh + bhh[r];
  }
}

// GRU gates -> h_new written to hnew_dst (scratch in fast path, final output
// row in fallback path).
__global__ __launch_bounds__(256) void k_gru2(
    const float* __restrict__ gi, const float* __restrict__ gh,
    const float* __restrict__ hs, float* __restrict__ hnew_dst) {
  const int i = threadIdx.x;
  const float* hprev = hs + (size_t)(kT - 1) * kH;
  float rr = 1.f / (1.f + expf(-(gi[i] + gh[i])));
  float z  = 1.f / (1.f + expf(-(gi[kH + i] + gh[kH + i])));
  float n  = tanhf(gi[2 * kH + i] + rr * gh[2 * kH + i]);
  hnew_dst[i] = (1.f - z) * n + z * hprev[i];
}

// ---------------------------------------------------------------------------
// Top-k phase 1: each block extracts its chunk's top-32 from LDS.
__global__ __launch_bounds__(256) void k_topk1(
    const float* __restrict__ alpha, float* __restrict__ candV,
    int* __restrict__ candI) {
  __shared__ float sv[kCHUNK];
  __shared__ float rv[4];
  __shared__ int ri[4];
  const int tid = threadIdx.x;
  const int base = blockIdx.x * kCHUNK;
  for (int i = tid; i < kCHUNK; i += 256) {
    int g = base + i;
    sv[i] = (g < kT) ? alpha[g] : -INFINITY;
  }
  __syncthreads();
  for (int k = 0; k < kK; ++k) {
    float bv = -INFINITY; int bi = -1;
    for (int i = tid; i < kCHUNK; i += 256) {
      float v = sv[i];
      if (v > bv) { bv = v; bi = i; }
    }
#pragma unroll
    for (int off = 32; off; off >>= 1) {
      float ov = __shfl_xor(bv, off);
      int   oi = __shfl_xor(bi, off);
      if (ov > bv || (ov == bv && oi != -1 && (bi == -1 || oi < bi))) { bv = ov; bi = oi; }
    }
    if ((tid & 63) == 0) { rv[tid >> 6] = bv; ri[tid >> 6] = bi; }
    __syncthreads();
    if (tid == 0) {
      float fv = rv[0]; int fi = ri[0];
      for (int j = 1; j < 4; ++j)
        if (rv[j] > fv || (rv[j] == fv && ri[j] != -1 && (fi == -1 || ri[j] < fi))) {
          fv = rv[j]; fi = ri[j];
        }
      candV[blockIdx.x * kK + k] = fv;
      candI[blockIdx.x * kK + k] = (fi >= 0) ? (base + fi) : 0;
      if (fi >= 0) sv[fi] = -INFINITY;
    }
    __syncthreads();
  }
}

// Top-k phase 2 + softmax + attention + pred (single block).
__global__ __launch_bounds__(256) void k_attn(
    const float* __restrict__ candV, const int* __restrict__ candI,
    const float* __restrict__ hs, const float* __restrict__ qh,
    const float* __restrict__ Ws, const float* __restrict__ bs,
    float* __restrict__ out) {
  __shared__ float sv[kNC];
  __shared__ float rv[4];
  __shared__ int ri[4];
  __shared__ float topv[kK];
  __shared__ int topi[kK];
  __shared__ float w[kK];
  __shared__ float red[256];
  const int tid = threadIdx.x;
  for (int i = tid; i < kNC; i += 256) sv[i] = candV[i];
  __syncthreads();
  for (int k = 0; k < kK; ++k) {
    float bv = -INFINITY; int bi = -1;
    for (int i = tid; i < kNC; i += 256) {
      float v = sv[i];
      if (v > bv) { bv = v; bi = i; }
    }
#pragma unroll
    for (int off = 32; off; off >>= 1) {
      float ov = __shfl_xor(bv, off);
      int   oi = __shfl_xor(bi, off);
      if (ov > bv || (ov == bv && oi != -1 && (bi == -1 || oi < bi))) { bv = ov; bi = oi; }
    }
    if ((tid & 63) == 0) { rv[tid >> 6] = bv; ri[tid >> 6] = bi; }
    __syncthreads();
    if (tid == 0) {
      float fv = rv[0]; int fi = ri[0];
      for (int j = 1; j < 4; ++j)
        if (rv[j] > fv || (rv[j] == fv && ri[j] != -1 && (fi == -1 || ri[j] < fi))) {
          fv = rv[j]; fi = ri[j];
        }
      topv[k] = fv;
      topi[k] = candI[fi];
      sv[fi] = -INFINITY;
    }
    __syncthreads();
  }
  if (tid == 0) {
    float m = topv[0];
    for (int j = 1; j < kK; ++j) m = fmaxf(m, topv[j]);
    float s = 0.f;
    for (int j = 0; j < kK; ++j) { w[j] = expf(topv[j] - m); s += w[j]; }
    float inv = 1.f / s;
    for (int j = 0; j < kK; ++j) w[j] *= inv;
  }
  __syncthreads();
  float a = 0.f;
#pragma unroll
  for (int j = 0; j < kK; ++j) a += w[j] * hs[(size_t)topi[j] * kH + tid];
  red[tid] = Ws[tid] * qh[tid] + Ws[kQ + tid] * a;
  __syncthreads();
  for (int s = 128; s; s >>= 1) {
    if (tid < s) red[tid] += red[tid + s];
    __syncthreads();
  }
  if (tid == 0) out[0] = red[0] + bs[0];
}

extern "C" void kernel_launch(void* const* d_in, const int* in_sizes, int n_in,
                              void* d_out, int out_size, void* d_ws, size_t ws_size,
                              hipStream_t stream) {
  const float* qh    = (const float*)d_in[0];
  const float* score = (const float*)d_in[1];
  const float* qs    = (const float*)d_in[2];
  const float* hs    = (const float*)d_in[3];
  const float* Wih   = (const float*)d_in[4];
  const float* Whh   = (const float*)d_in[5];
  const float* bih   = (const float*)d_in[6];
  const float* bhh   = (const float*)d_in[7];
  const float* Ws    = (const float*)d_in[8];
  const float* bs    = (const float*)d_in[9];
  float* out = (float*)d_out;

  const bool useWs = ws_size >= kScratchFloats * sizeof(float);
  // Fallback: scratch at start of hs_new output region, consumed before the
  // hs half of the copy overwrites it.
  float* S = useWs ? (float*)d_ws : (out + 1 + (size_t)(kT + 1) * kQ);
  float* alpha = S;                         // kT
  float* candV = S + kT;                    // kNC
  int*   candI = (int*)(S + kT + kNC);      // kNC
  float* gi    = S + kT + 2 * kNC;          // 768
  float* gh    = gi + kGruRows;             // 768
  float* hnew  = gh + kGruRows;             // 256 (16B-aligned offset)

  if (useWs) {
    hipLaunchKernelGGL(k_gru1, dim3(kGruBlocks), dim3(256), 0, stream,
                       Wih, Whh, bih, bhh, qh, hs, score, gi, gh);
    hipLaunchKernelGGL(k_gru2, dim3(1), dim3(256), 0, stream,
                       gi, gh, hs, hnew);
    hipLaunchKernelGGL(k_bigcopy, dim3(2048), dim3(256), 0, stream,
                       qs, hs, qh, hnew, out, alpha, 0, kRowsAll);
    hipLaunchKernelGGL(k_topk1, dim3(kNB1), dim3(256), 0, stream,
                       alpha, candV, candI);
    hipLaunchKernelGGL(k_attn, dim3(1), dim3(256), 0, stream,
                       candV, candI, hs, qh, Ws, bs, out);
  } else {
    // h_new goes straight to its final output row (region untouched below).
    float* hnewOut = out + 1 + (size_t)(kT + 1) * kQ + (size_t)kT * kH;
    hipLaunchKernelGGL(k_gru1, dim3(kGruBlocks), dim3(256), 0, stream,
                       Wih, Whh, bih, bhh, qh, hs, score, gi, gh);
    hipLaunchKernelGGL(k_gru2, dim3(1), dim3(256), 0, stream,
                       gi, gh, hs, hnewOut);
    hipLaunchKernelGGL(k_bigcopy, dim3(2048), dim3(256), 0, stream,
                       qs, hs, qh, hnewOut, out, alpha, 0, kRowsQs);
    hipLaunchKernelGGL(k_topk1, dim3(kNB1), dim3(256), 0, stream,
                       alpha, candV, candI);
    hipLaunchKernelGGL(k_attn, dim3(1), dim3(256), 0, stream,
                       candV, candI, hs, qh, Ws, bs, out);
    // hs rows [kT+1, 2kT+1) — overwrites scratch last; excludes h_new row.
    hipLaunchKernelGGL(k_bigcopy, dim3(2048), dim3(256), 0, stream,
                       qs, hs, qh, hnewOut, out, alpha, kRowsQs, 2 * kT + 1);
  }
}